// Round 13
// baseline (520.440 us; speedup 1.0000x reference)
//
#include <hip/hip_runtime.h>
#include <hip/hip_fp16.h>

#define LRELU(x) ((x) > 0.f ? (x) : 0.2f * (x))
#define SBSH 9      // 512 nodes per super-bucket
#define SBN 512
#define NB1 256     // blocks in count/append passes (each owns E/NB1 edges)
#define MAXSB 1024  // static LDS cap on super-bucket count
#define PC 16       // pool chunks per graph

// ---------------- small weights ----------------
// sw[0..2] = We1^T @ ae1 per edge-dim row; sw[3] = We2 . ae2; sw[4] = We3 . ae3
__global__ void small_weights_k(const float* __restrict__ We1, const float* __restrict__ ae1,
                                const float* __restrict__ We2, const float* __restrict__ ae2,
                                const float* __restrict__ We3, const float* __restrict__ ae3,
                                float* __restrict__ sw) {
  int t = threadIdx.x;  // 64 threads = 1 wave
  float v0 = We1[t] * ae1[t];
  float v1 = We1[64 + t] * ae1[t];
  float v2 = We1[128 + t] * ae1[t];
  float v3 = We2[t] * ae2[t];
  float v4 = (t < 32) ? We3[t] * ae3[t] : 0.f;
#pragma unroll
  for (int off = 32; off > 0; off >>= 1) {
    v0 += __shfl_down(v0, off);
    v1 += __shfl_down(v1, off);
    v2 += __shfl_down(v2, off);
    v3 += __shfl_down(v3, off);
    v4 += __shfl_down(v4, off);
  }
  if (t == 0) { sw[0] = v0; sw[1] = v1; sw[2] = v2; sw[3] = v3; sw[4] = v4; }
}

__global__ void zero_deg_k(int* __restrict__ deg, int m) {
  int i = blockIdx.x * 256 + threadIdx.x;
  if (i < m) deg[i] = 0;
}

// ---------------- CSR build, atomic-free staging ----------------
__global__ __launch_bounds__(256) void count1_k(const int* __restrict__ dst,
                                                int* __restrict__ gcnt, int E, int NSB) {
  __shared__ int cnt[MAXSB];
  const int t = threadIdx.x, blk = blockIdx.x;
  for (int i = t; i < NSB; i += 256) cnt[i] = 0;
  __syncthreads();
  const int CE = (E + NB1 - 1) / NB1;
  const int e0 = blk * CE, e1 = min(E, e0 + CE);
  for (int e = e0 + t; e < e1; e += 256) {
    int d = __builtin_nontemporal_load(&dst[e]);
    atomicAdd(&cnt[d >> SBSH], 1);
  }
  __syncthreads();
  for (int i = t; i < NSB; i += 256) gcnt[i * NB1 + blk] = cnt[i];  // sb-major
}

// hierarchical exclusive scan (generic): out[i] = block-local exclusive prefix
__global__ __launch_bounds__(1024) void scanA_k(const int* __restrict__ in,
                                                int* __restrict__ out,
                                                int* __restrict__ bsum, int M) {
  __shared__ int s[1024];
  const int t = threadIdx.x;
  const int i = blockIdx.x * 1024 + t;
  int v = (i < M) ? in[i] : 0;
  s[t] = v;
  __syncthreads();
  for (int off = 1; off < 1024; off <<= 1) {
    int add = (t >= off) ? s[t - off] : 0;
    __syncthreads();
    s[t] += add;
    __syncthreads();
  }
  if (i < M) out[i] = s[t] - v;  // block-local exclusive
  if (t == 1023) bsum[blockIdx.x] = s[t];
}

__global__ void scanB_k(const int* __restrict__ bsum, int* __restrict__ boff, int nb) {
  if (threadIdx.x == 0) {
    int acc = 0;
    for (int b = 0; b < nb; b++) { boff[b] = acc; acc += bsum[b]; }
  }
}

// variant for gbase: add block offsets + write sentinel gbase[M] = E
__global__ void scanC_gbase_k(int* __restrict__ gbase, const int* __restrict__ boff,
                              int M, int E) {
  int i = blockIdx.x * 256 + threadIdx.x;
  if (i < M) gbase[i] += boff[i >> 10];
  if (i == 0) gbase[M] = E;
}

// plain variant (rowptr: array includes its own sentinel via degExt[n]=0)
__global__ void scanC_plain_k(int* __restrict__ arr, const int* __restrict__ boff, int M) {
  int i = blockIdx.x * 256 + threadIdx.x;
  if (i < M) arr[i] += boff[i >> 10];
}

// S3: append into block-private reservations (LDS cursors, NO global atomics on
// positions) + per-node degree count (global atomics, deg is L2-resident).
// rec = { (loc 9b << 23) | src (23b), ae fp32 } packed in one int2
__global__ __launch_bounds__(256) void append2_k(
    const int* __restrict__ src, const int* __restrict__ dst,
    const float* __restrict__ eattr, const int* __restrict__ gbase,
    int2* __restrict__ recDS, int* __restrict__ deg,
    const float* __restrict__ sw, int E, int NSB) {
  __shared__ int base[MAXSB];
  __shared__ int off[MAXSB];
  const int t = threadIdx.x, blk = blockIdx.x;
  for (int i = t; i < NSB; i += 256) { base[i] = gbase[i * NB1 + blk]; off[i] = 0; }
  __syncthreads();
  const float w0 = sw[0], w1 = sw[1], w2 = sw[2];
  const int CE = (E + NB1 - 1) / NB1;
  const int e0 = blk * CE, e1 = min(E, e0 + CE);
  for (int e = e0 + t; e < e1; e += 256) {
    int d = __builtin_nontemporal_load(&dst[e]);
    int sv = __builtin_nontemporal_load(&src[e]);
    float a0 = __builtin_nontemporal_load(&eattr[e * 3]);
    float a1 = __builtin_nontemporal_load(&eattr[e * 3 + 1]);
    float a2 = __builtin_nontemporal_load(&eattr[e * 3 + 2]);
    float ae = a0 * w0 + a1 * w1 + a2 * w2;
    int sb = d >> SBSH;
    atomicAdd(&deg[d], 1);
    int pos = base[sb] + atomicAdd(&off[sb], 1);  // LDS atomic
    recDS[pos] = make_int2((int)(((unsigned)(d & (SBN - 1)) << 23) | (unsigned)sv),
                           __float_as_int(ae));
  }
}

// S4: one block per super-bucket, SINGLE sweep: place final edge[] =
// (src, layer-1 ex) using rowptr bases + LDS fill cursors; asum/esum in LDS.
__global__ __launch_bounds__(1024) void sb_build_k(
    const int2* __restrict__ recDS, const int* __restrict__ gbase,
    const int* __restrict__ rowptr, const float* __restrict__ asrc,
    const float* __restrict__ adst, float* __restrict__ asum,
    float* __restrict__ esum, int2* __restrict__ edge, int n, int NSB) {
  __shared__ int basev[SBN];
  __shared__ int fill[SBN];
  __shared__ float adl[SBN];
  __shared__ float rs[SBN];
  __shared__ float es[SBN];
  const int t = threadIdx.x, sb = blockIdx.x;
  const int v0 = sb << SBSH;
  const int nloc = min(SBN, n - v0);
  if (t < SBN) {
    fill[t] = 0; rs[t] = 0.f; es[t] = 0.f;
    basev[t] = (t < nloc) ? rowptr[v0 + t] : 0;
    adl[t] = (t < nloc) ? adst[v0 + t] : 0.f;
  }
  __syncthreads();
  const int seg0 = gbase[sb * NB1], seg1 = gbase[(sb + 1) * NB1];
  for (int i = seg0 + t; i < seg1; i += 1024) {
    int2 rec = recDS[i];
    unsigned q = (unsigned)rec.x;
    float ae = __int_as_float(rec.y);
    int loc = q >> 23;
    int sv = (int)(q & 0x7FFFFFu);
    int pos = basev[loc] + atomicAdd(&fill[loc], 1);
    float ex = __expf(LRELU(asrc[sv] + adl[loc] + ae));
    edge[pos] = make_int2(sv, __float_as_int(ex));
    atomicAdd(&rs[loc], ae);
    atomicAdd(&es[loc], ex);
  }
  __syncthreads();
  if (t < nloc) { asum[v0 + t] = rs[t]; esum[v0 + t] = es[t]; }
}

// ---------------- layer-1 GEMM: x [n,5] @ W [5,64] (wave per node) -------------

__global__ void gemm1_k(const float* __restrict__ x, const float* __restrict__ W,
                        const float* __restrict__ as, const float* __restrict__ ad,
                        __half* __restrict__ h, float* __restrict__ asrc,
                        float* __restrict__ adst, int n) {
  int lane = threadIdx.x & 63;
  int v = (blockIdx.x * blockDim.x + threadIdx.x) >> 6;
  if (v >= n) return;
  float acc = 0.f;
#pragma unroll
  for (int k = 0; k < 5; k++) acc += x[v * 5 + k] * W[k * 64 + lane];
  h[(size_t)v * 64 + lane] = __float2half(acc);
  float ps = acc * as[lane], pd = acc * ad[lane];
#pragma unroll
  for (int off = 32; off > 0; off >>= 1) {
    ps += __shfl_down(ps, off);
    pd += __shfl_down(pd, off);
  }
  if (lane == 0) { asrc[v] = ps; adst[v] = pd; }
}

// ------- tiled GEMM: x [n,64] (fp16) @ W [64,C] (fp32), 4x4 register blocking --

template <int C>
__global__ __launch_bounds__(256) void gemm_tile_k(
    const __half* __restrict__ x, const float* __restrict__ W,
    const float* __restrict__ as, const float* __restrict__ ad,
    __half* __restrict__ h, float* __restrict__ asrc, float* __restrict__ adst, int n) {
  constexpr int NT = 4096 / C;
  constexpr int CG = C / 4;
  constexpr int XTP = NT + 4;
  __shared__ float XT[64][XTP];
  __shared__ float Wl[64 * C];
  const int t = threadIdx.x;
  const int v0 = blockIdx.x * NT;
  for (int i = t; i < 64 * C; i += 256) Wl[i] = W[i];
  for (int i = t; i < NT * 32; i += 256) {
    int node = i >> 5, kk = (i & 31) << 1;
    int v = v0 + node;
    unsigned u = (v < n) ? *(const unsigned*)&x[(size_t)v * 64 + kk] : 0u;
    float2 f = __half22float2(*(const __half2*)&u);
    XT[kk][node] = f.x;
    XT[kk + 1][node] = f.y;
  }
  __syncthreads();
  const int cg = t % CG, ng = t / CG;
  const int c0 = cg * 4, n0 = ng * 4;
  float acc[4][4] = {};
#pragma unroll 4
  for (int k = 0; k < 64; ++k) {
    const float4 xv = *(const float4*)&XT[k][n0];
    const float4 wv = *(const float4*)&Wl[k * C + c0];
    acc[0][0] += xv.x * wv.x; acc[0][1] += xv.x * wv.y; acc[0][2] += xv.x * wv.z; acc[0][3] += xv.x * wv.w;
    acc[1][0] += xv.y * wv.x; acc[1][1] += xv.y * wv.y; acc[1][2] += xv.y * wv.z; acc[1][3] += xv.y * wv.w;
    acc[2][0] += xv.z * wv.x; acc[2][1] += xv.z * wv.y; acc[2][2] += xv.z * wv.z; acc[2][3] += xv.z * wv.w;
    acc[3][0] += xv.w * wv.x; acc[3][1] += xv.w * wv.y; acc[3][2] += xv.w * wv.z; acc[3][3] += xv.w * wv.w;
  }
  float asv[4] = {as[c0], as[c0 + 1], as[c0 + 2], as[c0 + 3]};
  float adv[4] = {ad[c0], ad[c0 + 1], ad[c0 + 2], ad[c0 + 3]};
  float ps[4], pd[4];
#pragma unroll
  for (int ni = 0; ni < 4; ++ni) {
    ps[ni] = acc[ni][0] * asv[0] + acc[ni][1] * asv[1] + acc[ni][2] * asv[2] + acc[ni][3] * asv[3];
    pd[ni] = acc[ni][0] * adv[0] + acc[ni][1] * adv[1] + acc[ni][2] * adv[2] + acc[ni][3] * adv[3];
  }
#pragma unroll
  for (int off = CG / 2; off > 0; off >>= 1) {
#pragma unroll
    for (int ni = 0; ni < 4; ++ni) {
      ps[ni] += __shfl_xor(ps[ni], off);
      pd[ni] += __shfl_xor(pd[ni], off);
    }
  }
#pragma unroll
  for (int ni = 0; ni < 4; ++ni) {
    int v = v0 + n0 + ni;
    if (v < n) {
      union { __half hh[4]; uint2 u; } pk;
      pk.hh[0] = __float2half(acc[ni][0]);
      pk.hh[1] = __float2half(acc[ni][1]);
      pk.hh[2] = __float2half(acc[ni][2]);
      pk.hh[3] = __float2half(acc[ni][3]);
      *(uint2*)&h[(size_t)v * C + c0] = pk.u;
      if (cg == 0) { asrc[v] = ps[ni]; adst[v] = pd[ni]; }
    }
  }
}

// 8 fp16 channels FMA into 4 float2 accumulators
__device__ __forceinline__ void fma8(float2* acc, float e, const uint4& u) {
  float2 f0 = __half22float2(*(const __half2*)&u.x);
  float2 f1 = __half22float2(*(const __half2*)&u.y);
  float2 f2 = __half22float2(*(const __half2*)&u.z);
  float2 f3 = __half22float2(*(const __half2*)&u.w);
  acc[0].x += e * f0.x; acc[0].y += e * f0.y;
  acc[1].x += e * f1.x; acc[1].y += e * f1.y;
  acc[2].x += e * f2.x; acc[2].y += e * f2.y;
  acc[3].x += e * f3.x; acc[3].y += e * f3.y;
}

// ---------------- per-node softmax + aggregate (two-sweep) --------------------
// edge[p] = (src, ex). LAYER=1: ex & den (esum) precomputed by sb_build — NO
// pass A. LAYER>=2: pass A lane-parallel, in-place ex update. Deferred
// normalization via pinv/oinv. Pass B: row-gather groups, 3 chains in flight.
// out: fp16 for LAYER<3 (next GEMM input), fp32 for LAYER==3 (pool input).
template <int LAYER, int C>
__global__ __launch_bounds__(256) void agg_k(
    const int* __restrict__ rowptr, int2* __restrict__ edge,
    const __half* __restrict__ h, const float* __restrict__ asrc,
    const float* __restrict__ adst, const float* __restrict__ asum,
    const float* __restrict__ esum, const float* __restrict__ pinv,
    const float* __restrict__ lp1, const float* __restrict__ lp2,
    float* __restrict__ oinv, float* __restrict__ ol1, float* __restrict__ ol2,
    const float* __restrict__ sw, const float* __restrict__ bias,
    void* __restrict__ outv, int n) {
  constexpr int L = (C == 64) ? 64 : 32;   // lanes per node
  constexpr int LPE = C / 8;               // lanes per h row (8 / 4)
  constexpr int EPI = L / LPE;             // edges per gather step (8)
  const int lane = threadIdx.x & 63;
  const int ln = lane & (L - 1);
  const int wid = (blockIdx.x * blockDim.x + threadIdx.x) >> 6;
  const int v = (C == 64) ? wid : wid * 2 + (lane >> 5);
  if (v >= n) return;
  const float s = (LAYER == 1) ? 1.f : (LAYER == 2 ? sw[3] : sw[4]);
  const float fac = (LAYER == 1) ? 1.f : pinv[v];
  const float sf = s * fac;
  const int r0 = rowptr[v], r1 = rowptr[v + 1];
  const float av_d = adst[v], av_s = asrc[v];

  // pass A (lane-parallel over edges); layer 1 skips it (den from esum)
  float rawsum = 0.f, den = 0.f;
  if (LAYER >= 2) {
    for (int p = r0 + ln; p < r1; p += L) {
      int2 pk = edge[p];
      float a = __int_as_float(pk.y);
      rawsum += a;
      float lg = asrc[pk.x] + av_d + sf * a;
      float ex = __expf(LRELU(lg));
      edge[p].y = __float_as_int(ex);
      den += ex;
    }
    __threadfence_block();
#pragma unroll
    for (int off = L / 2; off > 0; off >>= 1) {
      den += __shfl_xor(den, off);
      rawsum += __shfl_xor(rawsum, off);
    }
  } else {
    den = esum[v];
  }
  const float base = av_s + av_d;
  float la1 = 0.f, la2 = 0.f, e1 = 0.f, e2 = 0.f;
  if (LAYER >= 2) { la1 = fac * lp1[v]; e1 = __expf(LRELU(base + s * la1)); den += e1; }
  if (LAYER >= 3) { la2 = fac * lp2[v]; e2 = __expf(LRELU(base + s * la2)); den += e2; }
  int dd = (r1 - r0) + (LAYER - 1);
  if (dd < 1) dd = 1;
  float sum_a = (LAYER == 1) ? asum[v] : fac * rawsum + la1 + la2;
  float lmean = sum_a / (float)dd;
  float exm = __expf(LRELU(base + s * lmean));
  den += exm;
  float inv = 1.f / (den + 1e-16f);
  if (ln == 0) {
    if (LAYER < 3) oinv[v] = inv;
    if (LAYER == 1) ol1[v] = exm;
    if (LAYER == 2) { ol1[v] = e1; ol2[v] = exm; }
  }

  // pass B: group g handles edge p+g; lane's quad q covers channels [8q, 8q+8)
  const int g = ln / LPE;
  const int q = ln % LPE;
  const uint4* __restrict__ h4 = (const uint4*)h;
  float2 accA[4] = {{0.f,0.f},{0.f,0.f},{0.f,0.f},{0.f,0.f}};
  float2 accB[4] = {{0.f,0.f},{0.f,0.f},{0.f,0.f},{0.f,0.f}};
  int p = r0;
  for (; p + 3 * EPI <= r1; p += 3 * EPI) {  // 3 chains in flight
    int2 rA = edge[p + g];
    int2 rB = edge[p + EPI + g];
    int2 rC = edge[p + 2 * EPI + g];
    uint4 uA = h4[rA.x * LPE + q];
    uint4 uB = h4[rB.x * LPE + q];
    uint4 uC = h4[rC.x * LPE + q];
    fma8(accA, __int_as_float(rA.y), uA);
    fma8(accB, __int_as_float(rB.y), uB);
    fma8(accA, __int_as_float(rC.y), uC);
  }
  for (; p + EPI <= r1; p += EPI) {
    int2 rr = edge[p + g];
    uint4 u = h4[rr.x * LPE + q];
    fma8(accA, __int_as_float(rr.y), u);
  }
  if (p < r1) {  // masked tail (single partial group pass)
    int idx = p + g;
    int2 rr = (idx < r1) ? edge[idx] : edge[r1 - 1];
    float e_ = (idx < r1) ? __int_as_float(rr.y) : 0.f;
    uint4 u = h4[rr.x * LPE + q];
    fma8(accA, e_, u);
  }
#pragma unroll
  for (int j = 0; j < 4; ++j) {
    accA[j].x += accB[j].x;
    accA[j].y += accB[j].y;
  }
#pragma unroll
  for (int off = LPE; off < L; off <<= 1) {
#pragma unroll
    for (int j = 0; j < 4; ++j) {
      accA[j].x += __shfl_xor(accA[j].x, off);
      accA[j].y += __shfl_xor(accA[j].y, off);
    }
  }
  if (g == 0) {
    uint4 uh = h4[v * LPE + q];
    float2 f0 = __half22float2(*(const __half2*)&uh.x);
    float2 f1 = __half22float2(*(const __half2*)&uh.y);
    float2 f2 = __half22float2(*(const __half2*)&uh.z);
    float2 f3 = __half22float2(*(const __half2*)&uh.w);
    float sl = e1 + e2 + exm;
    float o[8];
    o[0] = (accA[0].x + sl * f0.x) * inv + bias[q * 8 + 0];
    o[1] = (accA[0].y + sl * f0.y) * inv + bias[q * 8 + 1];
    o[2] = (accA[1].x + sl * f1.x) * inv + bias[q * 8 + 2];
    o[3] = (accA[1].y + sl * f1.y) * inv + bias[q * 8 + 3];
    o[4] = (accA[2].x + sl * f2.x) * inv + bias[q * 8 + 4];
    o[5] = (accA[2].y + sl * f2.y) * inv + bias[q * 8 + 5];
    o[6] = (accA[3].x + sl * f3.x) * inv + bias[q * 8 + 6];
    o[7] = (accA[3].y + sl * f3.y) * inv + bias[q * 8 + 7];
    if (LAYER < 3) {  // relu + fp16 store (next layer's GEMM input)
      union { __half hh[8]; uint4 u; } pk;
#pragma unroll
      for (int j = 0; j < 8; ++j) pk.hh[j] = __float2half(fmaxf(o[j], 0.f));
      *(uint4*)&((__half*)outv)[(size_t)v * C + q * 8] = pk.u;
    } else {          // final layer: fp32 for pooling
      float4 o0 = make_float4(o[0], o[1], o[2], o[3]);
      float4 o1 = make_float4(o[4], o[5], o[6], o[7]);
      *(float4*)&((float*)outv)[(size_t)v * C + q * 8] = o0;
      *(float4*)&((float*)outv)[(size_t)v * C + q * 8 + 4] = o1;
    }
  }
}

// ---------------- global mean pool, two-stage (deterministic) ----------------

__global__ __launch_bounds__(256) void poolA_k(const float* __restrict__ h,
                                               const int* __restrict__ batch,
                                               float* __restrict__ partial, int n) {
  const int b = blockIdx.x;
  const int g = b / PC, ch = b % PC;
  int lo = 0, hi = n;
  while (lo < hi) { int m = (lo + hi) >> 1; if (batch[m] < g) lo = m + 1; else hi = m; }
  const int start = lo;
  hi = n;
  while (lo < hi) { int m = (lo + hi) >> 1; if (batch[m] < g + 1) lo = m + 1; else hi = m; }
  const int end = lo;
  const int len = end - start;
  const int c0 = start + (int)((long long)len * ch / PC);
  const int c1 = start + (int)((long long)len * (ch + 1) / PC);
  const int t = threadIdx.x;
  const int c = t & 31, r = t >> 5;
  float acc = 0.f;
  for (int v = c0 + r; v < c1; v += 8) acc += h[(size_t)v * 32 + c];
  __shared__ float sm[256];
  sm[t] = acc;
  __syncthreads();
  if (t < 128) sm[t] += sm[t + 128];
  __syncthreads();
  if (t < 64) sm[t] += sm[t + 64];
  __syncthreads();
  if (t < 32) partial[(b << 5) + t] = sm[t] + sm[t + 32];
}

__global__ void poolB_k(const float* __restrict__ partial, const int* __restrict__ batch,
                        float* __restrict__ out, int n) {
  const int g = blockIdx.x;
  const int t = threadIdx.x;
  if (t >= 32) return;
  int lo = 0, hi = n;
  while (lo < hi) { int m = (lo + hi) >> 1; if (batch[m] < g) lo = m + 1; else hi = m; }
  const int start = lo;
  hi = n;
  while (lo < hi) { int m = (lo + hi) >> 1; if (batch[m] < g + 1) lo = m + 1; else hi = m; }
  const int cnt = lo - start;
  float acc = 0.f;
#pragma unroll
  for (int ch = 0; ch < PC; ++ch) acc += partial[((g * PC + ch) << 5) + t];
  out[g * 32 + t] = acc / (float)(cnt > 0 ? cnt : 1);
}

// ---------------- launch ----------------

extern "C" void kernel_launch(void* const* d_in, const int* in_sizes, int n_in,
                              void* d_out, int out_size, void* d_ws, size_t ws_size,
                              hipStream_t stream) {
  const float* x     = (const float*)d_in[0];
  const int*   ei    = (const int*)d_in[1];
  const float* eattr = (const float*)d_in[2];
  const int*   batch = (const int*)d_in[3];
  const float *W1 = (const float*)d_in[4],  *as1 = (const float*)d_in[5],
              *ad1 = (const float*)d_in[6], *We1 = (const float*)d_in[7],
              *ae1 = (const float*)d_in[8], *b1  = (const float*)d_in[9];
  const float *W2 = (const float*)d_in[10], *as2 = (const float*)d_in[11],
              *ad2 = (const float*)d_in[12], *We2 = (const float*)d_in[13],
              *ae2 = (const float*)d_in[14], *b2  = (const float*)d_in[15];
  const float *W3 = (const float*)d_in[16], *as3 = (const float*)d_in[17],
              *ad3 = (const float*)d_in[18], *We3 = (const float*)d_in[19],
              *ae3 = (const float*)d_in[20], *b3  = (const float*)d_in[21];

  const int n = in_sizes[3];
  const int E = in_sizes[1] / 2;
  const int G = out_size / 32;
  const int* srcp = ei;
  const int* dstp = ei + E;
  const int NSB = (n + SBN - 1) >> SBSH;
  const int M = NSB * NB1;
  const int NBL = (M + 1023) / 1024;
  const int M2 = n + 1;                    // degExt length (deg[n] = 0 sentinel)
  const int NBL2 = (M2 + 1023) / 1024;

  char* w = (char*)d_ws;
  auto alloc = [&](size_t bytes) -> void* {
    void* p = (void*)w;
    w += (bytes + 255) & ~(size_t)255;
    return p;
  };
  // blob: staging recDS; after sb_build reused as Oh (fp16 inter) + O32 (final)
  size_t oh_bytes = ((size_t)n * 128 + 255) & ~(size_t)255;
  size_t blob_sz = (size_t)E * 8;
  if (blob_sz < oh_bytes + (size_t)n * 128) blob_sz = oh_bytes + (size_t)n * 128;
  char* blob = (char*)alloc(blob_sz);
  int2*   recDS = (int2*)blob;
  __half* Oh    = (__half*)blob;                    // n x 64 fp16
  float*  O32   = (float*)(blob + oh_bytes);        // n x 32 fp32
  int2*  edge  = (int2*)alloc((size_t)E * 8);
  __half* H    = (__half*)alloc((size_t)n * 64 * 2);
  int*   gcnt  = (int*)alloc((size_t)M * 4);
  int*   gbase = (int*)alloc((size_t)(M + 1) * 4);
  int*   bsum  = (int*)alloc((size_t)NBL * 4 + 256);
  int*   boff  = (int*)alloc((size_t)NBL * 4 + 256);
  int*   deg   = (int*)alloc((size_t)M2 * 4);       // per-node degree (+sentinel)
  int*   rowptr= (int*)alloc((size_t)(n + 1) * 4);
  int*   bsum2 = (int*)alloc((size_t)NBL2 * 4 + 256);
  int*   boff2 = (int*)alloc((size_t)NBL2 * 4 + 256);
  float* asum  = (float*)alloc((size_t)n * 4);
  float* esum  = (float*)alloc((size_t)n * 4);
  float* asrcB = (float*)alloc((size_t)n * 4);
  float* adstB = (float*)alloc((size_t)n * 4);
  float* loopA = (float*)alloc((size_t)n * 4);
  float* loopB1= (float*)alloc((size_t)n * 4);
  float* loopB2= (float*)alloc((size_t)n * 4);
  float* invA  = (float*)alloc((size_t)n * 4);
  float* invB  = (float*)alloc((size_t)n * 4);
  float* sw    = (float*)alloc(256);
  float* part  = (float*)alloc((size_t)G * PC * 32 * 4);

  dim3 blk256(256);
  dim3 gWave((n + 3) / 4);
  const int nw3 = (n + 1) / 2;
  dim3 gWave3((nw3 + 3) / 4);

  small_weights_k<<<1, 64, 0, stream>>>(We1, ae1, We2, ae2, We3, ae3, sw);
  zero_deg_k<<<dim3((M2 + 255) / 256), blk256, 0, stream>>>(deg, M2);
  count1_k<<<NB1, blk256, 0, stream>>>(dstp, gcnt, E, NSB);
  scanA_k<<<NBL, 1024, 0, stream>>>(gcnt, gbase, bsum, M);
  scanB_k<<<1, 64, 0, stream>>>(bsum, boff, NBL);
  scanC_gbase_k<<<dim3((M + 255) / 256), blk256, 0, stream>>>(gbase, boff, M, E);
  append2_k<<<NB1, blk256, 0, stream>>>(srcp, dstp, eattr, gbase, recDS, deg, sw, E, NSB);
  // rowptr = exclusive scan of degExt (deg[n]=0 sentinel -> rowptr[n]=E)
  scanA_k<<<NBL2, 1024, 0, stream>>>(deg, rowptr, bsum2, M2);
  scanB_k<<<1, 64, 0, stream>>>(bsum2, boff2, NBL2);
  scanC_plain_k<<<dim3((M2 + 255) / 256), blk256, 0, stream>>>(rowptr, boff2, M2);
  gemm1_k<<<gWave, blk256, 0, stream>>>(x, W1, as1, ad1, H, asrcB, adstB, n);
  sb_build_k<<<NSB, 1024, 0, stream>>>(recDS, gbase, rowptr, asrcB, adstB,
                                       asum, esum, edge, n, NSB);
  // layer 1 (out -> Oh fp16)
  agg_k<1, 64><<<gWave, blk256, 0, stream>>>(rowptr, edge, H, asrcB, adstB, asum, esum,
                                             nullptr, nullptr, nullptr,
                                             invA, loopA, nullptr, sw, b1, (void*)Oh, n);
  // layer 2
  gemm_tile_k<64><<<dim3((n + 63) / 64), blk256, 0, stream>>>(Oh, W2, as2, ad2, H, asrcB, adstB, n);
  agg_k<2, 64><<<gWave, blk256, 0, stream>>>(rowptr, edge, H, asrcB, adstB, nullptr, nullptr,
                                             invA, loopA, nullptr,
                                             invB, loopB1, loopB2, sw, b2, (void*)Oh, n);
  // layer 3 (out -> O32 fp32)
  gemm_tile_k<32><<<dim3((n + 127) / 128), blk256, 0, stream>>>(Oh, W3, as3, ad3, H, asrcB, adstB, n);
  agg_k<3, 32><<<gWave3, blk256, 0, stream>>>(rowptr, edge, H, asrcB, adstB, nullptr, nullptr,
                                              invB, loopB1, loopB2,
                                              nullptr, nullptr, nullptr, sw, b3, (void*)O32, n);
  // pool
  poolA_k<<<dim3(G * PC), blk256, 0, stream>>>(O32, batch, part, n);
  poolB_k<<<G, 64, 0, stream>>>(part, batch, (float*)d_out, n);
}

// Round 14
// 420.103 us; speedup vs baseline: 1.2388x; 1.2388x over previous
//
#include <hip/hip_runtime.h>
#include <hip/hip_fp16.h>

#define LRELU(x) ((x) > 0.f ? (x) : 0.2f * (x))
#define SBSH 9      // 512 nodes per super-bucket
#define SBN 512
#define NB1 1024    // blocks in count/append passes (each owns E/NB1 edges)
#define MAXSB 1024  // static LDS cap on super-bucket count
#define PC 16       // pool chunks per graph

// ---------------- small weights ----------------
// sw[0..2] = We1^T @ ae1 per edge-dim row; sw[3] = We2 . ae2; sw[4] = We3 . ae3
__global__ void small_weights_k(const float* __restrict__ We1, const float* __restrict__ ae1,
                                const float* __restrict__ We2, const float* __restrict__ ae2,
                                const float* __restrict__ We3, const float* __restrict__ ae3,
                                float* __restrict__ sw) {
  int t = threadIdx.x;  // 64 threads = 1 wave
  float v0 = We1[t] * ae1[t];
  float v1 = We1[64 + t] * ae1[t];
  float v2 = We1[128 + t] * ae1[t];
  float v3 = We2[t] * ae2[t];
  float v4 = (t < 32) ? We3[t] * ae3[t] : 0.f;
#pragma unroll
  for (int off = 32; off > 0; off >>= 1) {
    v0 += __shfl_down(v0, off);
    v1 += __shfl_down(v1, off);
    v2 += __shfl_down(v2, off);
    v3 += __shfl_down(v3, off);
    v4 += __shfl_down(v4, off);
  }
  if (t == 0) { sw[0] = v0; sw[1] = v1; sw[2] = v2; sw[3] = v3; sw[4] = v4; }
}

// ---------------- CSR build, atomic-free staging ----------------
__global__ __launch_bounds__(256) void count1_k(const int* __restrict__ dst,
                                                int* __restrict__ gcnt, int E, int NSB) {
  __shared__ int cnt[MAXSB];
  const int t = threadIdx.x, blk = blockIdx.x;
  for (int i = t; i < NSB; i += 256) cnt[i] = 0;
  __syncthreads();
  const int CE = (E + NB1 - 1) / NB1;
  const int e0 = blk * CE, e1 = min(E, e0 + CE);
  for (int e = e0 + t; e < e1; e += 256) {
    int d = __builtin_nontemporal_load(&dst[e]);
    atomicAdd(&cnt[d >> SBSH], 1);
  }
  __syncthreads();
  for (int i = t; i < NSB; i += 256) gcnt[i * NB1 + blk] = cnt[i];  // sb-major
}

// S2a/b/c: hierarchical exclusive scan over M counters
__global__ __launch_bounds__(1024) void scanA_k(const int* __restrict__ gcnt,
                                                int* __restrict__ gbase,
                                                int* __restrict__ bsum, int M) {
  __shared__ int s[1024];
  const int t = threadIdx.x;
  const int i = blockIdx.x * 1024 + t;
  int v = (i < M) ? gcnt[i] : 0;
  s[t] = v;
  __syncthreads();
  for (int off = 1; off < 1024; off <<= 1) {
    int add = (t >= off) ? s[t - off] : 0;
    __syncthreads();
    s[t] += add;
    __syncthreads();
  }
  if (i < M) gbase[i] = s[t] - v;  // block-local exclusive
  if (t == 1023) bsum[blockIdx.x] = s[t];
}

__global__ void scanB_k(const int* __restrict__ bsum, int* __restrict__ boff, int nb) {
  if (threadIdx.x == 0) {
    int acc = 0;
    for (int b = 0; b < nb; b++) { boff[b] = acc; acc += bsum[b]; }
  }
}

__global__ void scanC_k(int* __restrict__ gbase, const int* __restrict__ boff,
                        int* __restrict__ rowptr, int M, int E) {
  int i = blockIdx.x * 256 + threadIdx.x;
  if (i < M) gbase[i] += boff[i >> 10];
  if (i == 0) { gbase[M] = E; rowptr[0] = 0; }
}

// S3: append into block-private reservations (LDS cursors, NO global atomics)
// rec = { (loc 9b << 23) | src (23b), ae fp32 } packed in one int2
__global__ __launch_bounds__(256) void append2_k(
    const int* __restrict__ src, const int* __restrict__ dst,
    const float* __restrict__ eattr, const int* __restrict__ gbase,
    int2* __restrict__ recDS, const float* __restrict__ sw, int E, int NSB) {
  __shared__ int base[MAXSB];
  __shared__ int off[MAXSB];
  const int t = threadIdx.x, blk = blockIdx.x;
  for (int i = t; i < NSB; i += 256) { base[i] = gbase[i * NB1 + blk]; off[i] = 0; }
  __syncthreads();
  const float w0 = sw[0], w1 = sw[1], w2 = sw[2];
  const int CE = (E + NB1 - 1) / NB1;
  const int e0 = blk * CE, e1 = min(E, e0 + CE);
  for (int e = e0 + t; e < e1; e += 256) {
    int d = __builtin_nontemporal_load(&dst[e]);
    int sv = __builtin_nontemporal_load(&src[e]);
    float a0 = __builtin_nontemporal_load(&eattr[e * 3]);
    float a1 = __builtin_nontemporal_load(&eattr[e * 3 + 1]);
    float a2 = __builtin_nontemporal_load(&eattr[e * 3 + 2]);
    float ae = a0 * w0 + a1 * w1 + a2 * w2;
    int sb = d >> SBSH;
    int pos = base[sb] + atomicAdd(&off[sb], 1);  // LDS atomic
    recDS[pos] = make_int2((int)(((unsigned)(d & (SBN - 1)) << 23) | (unsigned)sv),
                           __float_as_int(ae));
  }
}

// S4: one block per super-bucket: count 512 nodes, block-scan -> rowptr,
// place final edge[] = (src, layer-1 ex); asum (raw attr) + esum (Σ ex) in LDS.
__global__ __launch_bounds__(1024) void sb_build_k(
    const int2* __restrict__ recDS, const int* __restrict__ gbase,
    const float* __restrict__ asrc, const float* __restrict__ adst,
    int* __restrict__ rowptr, float* __restrict__ asum, float* __restrict__ esum,
    int2* __restrict__ edge, int n, int NSB) {
  __shared__ int cnt[SBN];
  __shared__ int sc[SBN];
  __shared__ int fill[SBN];
  __shared__ float adl[SBN];
  __shared__ float rs[SBN];
  __shared__ float es[SBN];
  const int t = threadIdx.x, sb = blockIdx.x;
  const int v0 = sb << SBSH;
  const int nloc = min(SBN, n - v0);
  if (t < SBN) {
    cnt[t] = 0; fill[t] = 0; rs[t] = 0.f; es[t] = 0.f;
    adl[t] = (t < nloc) ? adst[v0 + t] : 0.f;
  }
  __syncthreads();
  const int seg0 = gbase[sb * NB1], seg1 = gbase[(sb + 1) * NB1];
  for (int i = seg0 + t; i < seg1; i += 1024)
    atomicAdd(&cnt[(unsigned)recDS[i].x >> 23], 1);
  __syncthreads();
  if (t < SBN) sc[t] = cnt[t];
  __syncthreads();
  for (int off = 1; off < SBN; off <<= 1) {
    int add = (t < SBN && t >= off) ? sc[t - off] : 0;
    __syncthreads();
    if (t < SBN) sc[t] += add;
    __syncthreads();
  }
  if (t < nloc) rowptr[v0 + t + 1] = seg0 + sc[t];
  for (int i = seg0 + t; i < seg1; i += 1024) {
    int2 rec = recDS[i];
    unsigned q = (unsigned)rec.x;
    float ae = __int_as_float(rec.y);
    int loc = q >> 23;
    int sv = (int)(q & 0x7FFFFFu);
    int pos = seg0 + (sc[loc] - cnt[loc]) + atomicAdd(&fill[loc], 1);
    float ex = __expf(LRELU(asrc[sv] + adl[loc] + ae));
    edge[pos] = make_int2(sv, __float_as_int(ex));
    atomicAdd(&rs[loc], ae);
    atomicAdd(&es[loc], ex);
  }
  __syncthreads();
  if (t < nloc) { asum[v0 + t] = rs[t]; esum[v0 + t] = es[t]; }
}

// ---------------- layer-1 GEMM: x [n,5] @ W [5,64] (wave per node) -------------

__global__ void gemm1_k(const float* __restrict__ x, const float* __restrict__ W,
                        const float* __restrict__ as, const float* __restrict__ ad,
                        __half* __restrict__ h, float* __restrict__ asrc,
                        float* __restrict__ adst, int n) {
  int lane = threadIdx.x & 63;
  int v = (blockIdx.x * blockDim.x + threadIdx.x) >> 6;
  if (v >= n) return;
  float acc = 0.f;
#pragma unroll
  for (int k = 0; k < 5; k++) acc += x[v * 5 + k] * W[k * 64 + lane];
  h[(size_t)v * 64 + lane] = __float2half(acc);
  float ps = acc * as[lane], pd = acc * ad[lane];
#pragma unroll
  for (int off = 32; off > 0; off >>= 1) {
    ps += __shfl_down(ps, off);
    pd += __shfl_down(pd, off);
  }
  if (lane == 0) { asrc[v] = ps; adst[v] = pd; }
}

// ------- tiled GEMM: x [n,64] (fp16) @ W [64,C] (fp32), 4x4 register blocking --

template <int C>
__global__ __launch_bounds__(256) void gemm_tile_k(
    const __half* __restrict__ x, const float* __restrict__ W,
    const float* __restrict__ as, const float* __restrict__ ad,
    __half* __restrict__ h, float* __restrict__ asrc, float* __restrict__ adst, int n) {
  constexpr int NT = 4096 / C;
  constexpr int CG = C / 4;
  constexpr int XTP = NT + 4;
  __shared__ float XT[64][XTP];
  __shared__ float Wl[64 * C];
  const int t = threadIdx.x;
  const int v0 = blockIdx.x * NT;
  for (int i = t; i < 64 * C; i += 256) Wl[i] = W[i];
  for (int i = t; i < NT * 32; i += 256) {
    int node = i >> 5, kk = (i & 31) << 1;
    int v = v0 + node;
    unsigned u = (v < n) ? *(const unsigned*)&x[(size_t)v * 64 + kk] : 0u;
    float2 f = __half22float2(*(const __half2*)&u);
    XT[kk][node] = f.x;
    XT[kk + 1][node] = f.y;
  }
  __syncthreads();
  const int cg = t % CG, ng = t / CG;
  const int c0 = cg * 4, n0 = ng * 4;
  float acc[4][4] = {};
#pragma unroll 4
  for (int k = 0; k < 64; ++k) {
    const float4 xv = *(const float4*)&XT[k][n0];
    const float4 wv = *(const float4*)&Wl[k * C + c0];
    acc[0][0] += xv.x * wv.x; acc[0][1] += xv.x * wv.y; acc[0][2] += xv.x * wv.z; acc[0][3] += xv.x * wv.w;
    acc[1][0] += xv.y * wv.x; acc[1][1] += xv.y * wv.y; acc[1][2] += xv.y * wv.z; acc[1][3] += xv.y * wv.w;
    acc[2][0] += xv.z * wv.x; acc[2][1] += xv.z * wv.y; acc[2][2] += xv.z * wv.z; acc[2][3] += xv.z * wv.w;
    acc[3][0] += xv.w * wv.x; acc[3][1] += xv.w * wv.y; acc[3][2] += xv.w * wv.z; acc[3][3] += xv.w * wv.w;
  }
  float asv[4] = {as[c0], as[c0 + 1], as[c0 + 2], as[c0 + 3]};
  float adv[4] = {ad[c0], ad[c0 + 1], ad[c0 + 2], ad[c0 + 3]};
  float ps[4], pd[4];
#pragma unroll
  for (int ni = 0; ni < 4; ++ni) {
    ps[ni] = acc[ni][0] * asv[0] + acc[ni][1] * asv[1] + acc[ni][2] * asv[2] + acc[ni][3] * asv[3];
    pd[ni] = acc[ni][0] * adv[0] + acc[ni][1] * adv[1] + acc[ni][2] * adv[2] + acc[ni][3] * adv[3];
  }
#pragma unroll
  for (int off = CG / 2; off > 0; off >>= 1) {
#pragma unroll
    for (int ni = 0; ni < 4; ++ni) {
      ps[ni] += __shfl_xor(ps[ni], off);
      pd[ni] += __shfl_xor(pd[ni], off);
    }
  }
#pragma unroll
  for (int ni = 0; ni < 4; ++ni) {
    int v = v0 + n0 + ni;
    if (v < n) {
      union { __half hh[4]; uint2 u; } pk;
      pk.hh[0] = __float2half(acc[ni][0]);
      pk.hh[1] = __float2half(acc[ni][1]);
      pk.hh[2] = __float2half(acc[ni][2]);
      pk.hh[3] = __float2half(acc[ni][3]);
      *(uint2*)&h[(size_t)v * C + c0] = pk.u;
      if (cg == 0) { asrc[v] = ps[ni]; adst[v] = pd[ni]; }
    }
  }
}

// 8 fp16 channels FMA into 4 float2 accumulators
__device__ __forceinline__ void fma8(float2* acc, float e, const uint4& u) {
  float2 f0 = __half22float2(*(const __half2*)&u.x);
  float2 f1 = __half22float2(*(const __half2*)&u.y);
  float2 f2 = __half22float2(*(const __half2*)&u.z);
  float2 f3 = __half22float2(*(const __half2*)&u.w);
  acc[0].x += e * f0.x; acc[0].y += e * f0.y;
  acc[1].x += e * f1.x; acc[1].y += e * f1.y;
  acc[2].x += e * f2.x; acc[2].y += e * f2.y;
  acc[3].x += e * f3.x; acc[3].y += e * f3.y;
}

// ---------------- per-node softmax + aggregate (round-10 structure) -----------
// edge[p] = (src, ex). LAYER=1: ex & den (esum) precomputed by sb_build — NO
// pass A. LAYER>=2: pass A lane-parallel (1 edge/lane/iter), in-place ex update.
// Deferred normalization via pinv/oinv. Pass B: row-gather groups, 2 chains.
// out: fp16 for LAYER<3 (next GEMM input), fp32 for LAYER==3 (pool input).
template <int LAYER, int C>
__global__ __launch_bounds__(256) void agg_k(
    const int* __restrict__ rowptr, int2* __restrict__ edge,
    const __half* __restrict__ h, const float* __restrict__ asrc,
    const float* __restrict__ adst, const float* __restrict__ asum,
    const float* __restrict__ esum, const float* __restrict__ pinv,
    const float* __restrict__ lp1, const float* __restrict__ lp2,
    float* __restrict__ oinv, float* __restrict__ ol1, float* __restrict__ ol2,
    const float* __restrict__ sw, const float* __restrict__ bias,
    void* __restrict__ outv, int n) {
  constexpr int L = (C == 64) ? 64 : 32;   // lanes per node
  constexpr int LPE = C / 8;               // lanes per h row (8 / 4)
  constexpr int EPI = L / LPE;             // edges per iteration (8)
  const int lane = threadIdx.x & 63;
  const int ln = lane & (L - 1);
  const int wid = (blockIdx.x * blockDim.x + threadIdx.x) >> 6;
  const int v = (C == 64) ? wid : wid * 2 + (lane >> 5);
  if (v >= n) return;
  const float s = (LAYER == 1) ? 1.f : (LAYER == 2 ? sw[3] : sw[4]);
  const float fac = (LAYER == 1) ? 1.f : pinv[v];
  const float sf = s * fac;
  const int r0 = rowptr[v], r1 = rowptr[v + 1];
  const float av_d = adst[v], av_s = asrc[v];

  // pass A (lane-parallel over edges); layer 1 skips it (den from esum)
  float rawsum = 0.f, den = 0.f;
  if (LAYER >= 2) {
    for (int p = r0 + ln; p < r1; p += L) {
      int2 pk = edge[p];
      float a = __int_as_float(pk.y);
      rawsum += a;
      float lg = asrc[pk.x] + av_d + sf * a;
      float ex = __expf(LRELU(lg));
      edge[p].y = __float_as_int(ex);
      den += ex;
    }
    __threadfence_block();
#pragma unroll
    for (int off = L / 2; off > 0; off >>= 1) {
      den += __shfl_xor(den, off);
      rawsum += __shfl_xor(rawsum, off);
    }
  } else {
    den = esum[v];
  }
  const float base = av_s + av_d;
  float la1 = 0.f, la2 = 0.f, e1 = 0.f, e2 = 0.f;
  if (LAYER >= 2) { la1 = fac * lp1[v]; e1 = __expf(LRELU(base + s * la1)); den += e1; }
  if (LAYER >= 3) { la2 = fac * lp2[v]; e2 = __expf(LRELU(base + s * la2)); den += e2; }
  int dd = (r1 - r0) + (LAYER - 1);
  if (dd < 1) dd = 1;
  float sum_a = (LAYER == 1) ? asum[v] : fac * rawsum + la1 + la2;
  float lmean = sum_a / (float)dd;
  float exm = __expf(LRELU(base + s * lmean));
  den += exm;
  float inv = 1.f / (den + 1e-16f);
  if (ln == 0) {
    if (LAYER < 3) oinv[v] = inv;
    if (LAYER == 1) ol1[v] = exm;
    if (LAYER == 2) { ol1[v] = e1; ol2[v] = exm; }
  }

  // pass B: group g handles edge p+g; lane's quad q covers channels [8q, 8q+8)
  const int g = ln / LPE;
  const int q = ln % LPE;
  const uint4* __restrict__ h4 = (const uint4*)h;
  float2 accA[4] = {{0.f,0.f},{0.f,0.f},{0.f,0.f},{0.f,0.f}};
  float2 accB[4] = {{0.f,0.f},{0.f,0.f},{0.f,0.f},{0.f,0.f}};
  int p = r0;
  for (; p + 2 * EPI <= r1; p += 2 * EPI) {
    int2 rA = edge[p + g];
    int2 rB = edge[p + EPI + g];
    uint4 uA = h4[rA.x * LPE + q];
    uint4 uB = h4[rB.x * LPE + q];
    fma8(accA, __int_as_float(rA.y), uA);
    fma8(accB, __int_as_float(rB.y), uB);
  }
  for (; p < r1; p += EPI) {
    int idx = p + g;
    float e_;
    int2 rr;
    if (idx < r1) { rr = edge[idx]; e_ = __int_as_float(rr.y); }
    else { rr = edge[r1 - 1]; e_ = 0.f; }
    uint4 u = h4[rr.x * LPE + q];
    fma8(accA, e_, u);
  }
#pragma unroll
  for (int j = 0; j < 4; ++j) {
    accA[j].x += accB[j].x;
    accA[j].y += accB[j].y;
  }
#pragma unroll
  for (int off = LPE; off < L; off <<= 1) {
#pragma unroll
    for (int j = 0; j < 4; ++j) {
      accA[j].x += __shfl_xor(accA[j].x, off);
      accA[j].y += __shfl_xor(accA[j].y, off);
    }
  }
  if (g == 0) {
    uint4 uh = h4[v * LPE + q];
    float2 f0 = __half22float2(*(const __half2*)&uh.x);
    float2 f1 = __half22float2(*(const __half2*)&uh.y);
    float2 f2 = __half22float2(*(const __half2*)&uh.z);
    float2 f3 = __half22float2(*(const __half2*)&uh.w);
    float sl = e1 + e2 + exm;
    float o[8];
    o[0] = (accA[0].x + sl * f0.x) * inv + bias[q * 8 + 0];
    o[1] = (accA[0].y + sl * f0.y) * inv + bias[q * 8 + 1];
    o[2] = (accA[1].x + sl * f1.x) * inv + bias[q * 8 + 2];
    o[3] = (accA[1].y + sl * f1.y) * inv + bias[q * 8 + 3];
    o[4] = (accA[2].x + sl * f2.x) * inv + bias[q * 8 + 4];
    o[5] = (accA[2].y + sl * f2.y) * inv + bias[q * 8 + 5];
    o[6] = (accA[3].x + sl * f3.x) * inv + bias[q * 8 + 6];
    o[7] = (accA[3].y + sl * f3.y) * inv + bias[q * 8 + 7];
    if (LAYER < 3) {  // relu + fp16 store (next layer's GEMM input)
      union { __half hh[8]; uint4 u; } pk;
#pragma unroll
      for (int j = 0; j < 8; ++j) pk.hh[j] = __float2half(fmaxf(o[j], 0.f));
      *(uint4*)&((__half*)outv)[(size_t)v * C + q * 8] = pk.u;
    } else {          // final layer: fp32 for pooling
      float4 o0 = make_float4(o[0], o[1], o[2], o[3]);
      float4 o1 = make_float4(o[4], o[5], o[6], o[7]);
      *(float4*)&((float*)outv)[(size_t)v * C + q * 8] = o0;
      *(float4*)&((float*)outv)[(size_t)v * C + q * 8 + 4] = o1;
    }
  }
}

// ---------------- global mean pool, two-stage (deterministic) ----------------

__global__ __launch_bounds__(256) void poolA_k(const float* __restrict__ h,
                                               const int* __restrict__ batch,
                                               float* __restrict__ partial, int n) {
  const int b = blockIdx.x;
  const int g = b / PC, ch = b % PC;
  int lo = 0, hi = n;
  while (lo < hi) { int m = (lo + hi) >> 1; if (batch[m] < g) lo = m + 1; else hi = m; }
  const int start = lo;
  hi = n;
  while (lo < hi) { int m = (lo + hi) >> 1; if (batch[m] < g + 1) lo = m + 1; else hi = m; }
  const int end = lo;
  const int len = end - start;
  const int c0 = start + (int)((long long)len * ch / PC);
  const int c1 = start + (int)((long long)len * (ch + 1) / PC);
  const int t = threadIdx.x;
  const int c = t & 31, r = t >> 5;
  float acc = 0.f;
  for (int v = c0 + r; v < c1; v += 8) acc += h[(size_t)v * 32 + c];
  __shared__ float sm[256];
  sm[t] = acc;
  __syncthreads();
  if (t < 128) sm[t] += sm[t + 128];
  __syncthreads();
  if (t < 64) sm[t] += sm[t + 64];
  __syncthreads();
  if (t < 32) partial[(b << 5) + t] = sm[t] + sm[t + 32];
}

__global__ void poolB_k(const float* __restrict__ partial, const int* __restrict__ batch,
                        float* __restrict__ out, int n) {
  const int g = blockIdx.x;
  const int t = threadIdx.x;
  if (t >= 32) return;
  int lo = 0, hi = n;
  while (lo < hi) { int m = (lo + hi) >> 1; if (batch[m] < g) lo = m + 1; else hi = m; }
  const int start = lo;
  hi = n;
  while (lo < hi) { int m = (lo + hi) >> 1; if (batch[m] < g + 1) lo = m + 1; else hi = m; }
  const int cnt = lo - start;
  float acc = 0.f;
#pragma unroll
  for (int ch = 0; ch < PC; ++ch) acc += partial[((g * PC + ch) << 5) + t];
  out[g * 32 + t] = acc / (float)(cnt > 0 ? cnt : 1);
}

// ---------------- launch ----------------

extern "C" void kernel_launch(void* const* d_in, const int* in_sizes, int n_in,
                              void* d_out, int out_size, void* d_ws, size_t ws_size,
                              hipStream_t stream) {
  const float* x     = (const float*)d_in[0];
  const int*   ei    = (const int*)d_in[1];
  const float* eattr = (const float*)d_in[2];
  const int*   batch = (const int*)d_in[3];
  const float *W1 = (const float*)d_in[4],  *as1 = (const float*)d_in[5],
              *ad1 = (const float*)d_in[6], *We1 = (const float*)d_in[7],
              *ae1 = (const float*)d_in[8], *b1  = (const float*)d_in[9];
  const float *W2 = (const float*)d_in[10], *as2 = (const float*)d_in[11],
              *ad2 = (const float*)d_in[12], *We2 = (const float*)d_in[13],
              *ae2 = (const float*)d_in[14], *b2  = (const float*)d_in[15];
  const float *W3 = (const float*)d_in[16], *as3 = (const float*)d_in[17],
              *ad3 = (const float*)d_in[18], *We3 = (const float*)d_in[19],
              *ae3 = (const float*)d_in[20], *b3  = (const float*)d_in[21];

  const int n = in_sizes[3];
  const int E = in_sizes[1] / 2;
  const int G = out_size / 32;
  const int* srcp = ei;
  const int* dstp = ei + E;
  const int NSB = (n + SBN - 1) >> SBSH;
  const int M = NSB * NB1;
  const int NBL = (M + 1023) / 1024;

  char* w = (char*)d_ws;
  auto alloc = [&](size_t bytes) -> void* {
    void* p = (void*)w;
    w += (bytes + 255) & ~(size_t)255;
    return p;
  };
  // blob: staging recDS; after sb_build reused as Oh (fp16 inter) + O32 (final)
  size_t oh_bytes = ((size_t)n * 128 + 255) & ~(size_t)255;
  size_t blob_sz = (size_t)E * 8;
  if (blob_sz < oh_bytes + (size_t)n * 128) blob_sz = oh_bytes + (size_t)n * 128;
  char* blob = (char*)alloc(blob_sz);
  int2*   recDS = (int2*)blob;
  __half* Oh    = (__half*)blob;                    // n x 64 fp16
  float*  O32   = (float*)(blob + oh_bytes);        // n x 32 fp32
  int2*  edge  = (int2*)alloc((size_t)E * 8);
  __half* H    = (__half*)alloc((size_t)n * 64 * 2);
  int*   gcnt  = (int*)alloc((size_t)M * 4);
  int*   gbase = (int*)alloc((size_t)(M + 1) * 4);
  int*   bsum  = (int*)alloc((size_t)NBL * 4 + 256);
  int*   boff  = (int*)alloc((size_t)NBL * 4 + 256);
  int*   rowptr= (int*)alloc((size_t)(n + 1) * 4);
  float* asum  = (float*)alloc((size_t)n * 4);
  float* esum  = (float*)alloc((size_t)n * 4);
  float* asrcB = (float*)alloc((size_t)n * 4);
  float* adstB = (float*)alloc((size_t)n * 4);
  float* loopA = (float*)alloc((size_t)n * 4);
  float* loopB1= (float*)alloc((size_t)n * 4);
  float* loopB2= (float*)alloc((size_t)n * 4);
  float* invA  = (float*)alloc((size_t)n * 4);
  float* invB  = (float*)alloc((size_t)n * 4);
  float* sw    = (float*)alloc(256);
  float* part  = (float*)alloc((size_t)G * PC * 32 * 4);

  dim3 blk256(256);
  dim3 gWave((n + 3) / 4);
  const int nw3 = (n + 1) / 2;
  dim3 gWave3((nw3 + 3) / 4);

  small_weights_k<<<1, 64, 0, stream>>>(We1, ae1, We2, ae2, We3, ae3, sw);
  count1_k<<<NB1, blk256, 0, stream>>>(dstp, gcnt, E, NSB);
  scanA_k<<<NBL, 1024, 0, stream>>>(gcnt, gbase, bsum, M);
  scanB_k<<<1, 64, 0, stream>>>(bsum, boff, NBL);
  scanC_k<<<dim3((M + 256) / 256), blk256, 0, stream>>>(gbase, boff, rowptr, M, E);
  append2_k<<<NB1, blk256, 0, stream>>>(srcp, dstp, eattr, gbase, recDS, sw, E, NSB);
  gemm1_k<<<gWave, blk256, 0, stream>>>(x, W1, as1, ad1, H, asrcB, adstB, n);
  sb_build_k<<<NSB, 1024, 0, stream>>>(recDS, gbase, asrcB, adstB,
                                       rowptr, asum, esum, edge, n, NSB);
  // layer 1 (out -> Oh fp16)
  agg_k<1, 64><<<gWave, blk256, 0, stream>>>(rowptr, edge, H, asrcB, adstB, asum, esum,
                                             nullptr, nullptr, nullptr,
                                             invA, loopA, nullptr, sw, b1, (void*)Oh, n);
  // layer 2
  gemm_tile_k<64><<<dim3((n + 63) / 64), blk256, 0, stream>>>(Oh, W2, as2, ad2, H, asrcB, adstB, n);
  agg_k<2, 64><<<gWave, blk256, 0, stream>>>(rowptr, edge, H, asrcB, adstB, nullptr, nullptr,
                                             invA, loopA, nullptr,
                                             invB, loopB1, loopB2, sw, b2, (void*)Oh, n);
  // layer 3 (out -> O32 fp32)
  gemm_tile_k<32><<<dim3((n + 127) / 128), blk256, 0, stream>>>(Oh, W3, as3, ad3, H, asrcB, adstB, n);
  agg_k<3, 32><<<gWave3, blk256, 0, stream>>>(rowptr, edge, H, asrcB, adstB, nullptr, nullptr,
                                              invB, loopB1, loopB2,
                                              nullptr, nullptr, nullptr, sw, b3, (void*)O32, n);
  // pool
  poolA_k<<<dim3(G * PC), blk256, 0, stream>>>(O32, batch, part, n);
  poolB_k<<<G, 64, 0, stream>>>(part, batch, (float*)d_out, n);
}

// Round 15
// 390.758 us; speedup vs baseline: 1.3319x; 1.0751x over previous
//
#include <hip/hip_runtime.h>
#include <hip/hip_fp16.h>

#define LRELU(x) ((x) > 0.f ? (x) : 0.2f * (x))
#define SBSH 9      // 512 nodes per super-bucket
#define SBN 512
#define NB1 1024    // blocks in count/append passes (each owns E/NB1 edges)
#define MAXSB 1024  // static LDS cap on super-bucket count
#define PC 16       // pool chunks per graph

// ---------------- small weights ----------------
// sw[0..2] = We1^T @ ae1 per edge-dim row; sw[3] = We2 . ae2; sw[4] = We3 . ae3
__global__ void small_weights_k(const float* __restrict__ We1, const float* __restrict__ ae1,
                                const float* __restrict__ We2, const float* __restrict__ ae2,
                                const float* __restrict__ We3, const float* __restrict__ ae3,
                                float* __restrict__ sw) {
  int t = threadIdx.x;  // 64 threads = 1 wave
  float v0 = We1[t] * ae1[t];
  float v1 = We1[64 + t] * ae1[t];
  float v2 = We1[128 + t] * ae1[t];
  float v3 = We2[t] * ae2[t];
  float v4 = (t < 32) ? We3[t] * ae3[t] : 0.f;
#pragma unroll
  for (int off = 32; off > 0; off >>= 1) {
    v0 += __shfl_down(v0, off);
    v1 += __shfl_down(v1, off);
    v2 += __shfl_down(v2, off);
    v3 += __shfl_down(v3, off);
    v4 += __shfl_down(v4, off);
  }
  if (t == 0) { sw[0] = v0; sw[1] = v1; sw[2] = v2; sw[3] = v3; sw[4] = v4; }
}

// ---------------- CSR build, atomic-free staging ----------------
// S1: per-(super-bucket, block) exact counts; int4 loads (4 edges/iter/thread).
__global__ __launch_bounds__(256) void count1_k(const int* __restrict__ dst,
                                                int* __restrict__ gcnt, int E, int NSB,
                                                int CE) {
  __shared__ int cnt[MAXSB];
  const int t = threadIdx.x, blk = blockIdx.x;
  for (int i = t; i < NSB; i += 256) cnt[i] = 0;
  __syncthreads();
  const int e0 = blk * CE;
  const int e1 = min(E, e0 + CE);
  const int len = e1 - e0;
  if (len > 0) {
    const int NQ = len >> 2;
    for (int i = t; i < NQ; i += 256) {
      int4 d4 = *(const int4*)&dst[e0 + 4 * i];
      atomicAdd(&cnt[d4.x >> SBSH], 1);
      atomicAdd(&cnt[d4.y >> SBSH], 1);
      atomicAdd(&cnt[d4.z >> SBSH], 1);
      atomicAdd(&cnt[d4.w >> SBSH], 1);
    }
    const int rem = len & 3;
    if (t < rem) atomicAdd(&cnt[dst[e0 + (NQ << 2) + t] >> SBSH], 1);
  }
  __syncthreads();
  for (int i = t; i < NSB; i += 256) gcnt[i * NB1 + blk] = cnt[i];  // sb-major
}

// S2a/b/c: hierarchical exclusive scan over M counters
__global__ __launch_bounds__(1024) void scanA_k(const int* __restrict__ gcnt,
                                                int* __restrict__ gbase,
                                                int* __restrict__ bsum, int M) {
  __shared__ int s[1024];
  const int t = threadIdx.x;
  const int i = blockIdx.x * 1024 + t;
  int v = (i < M) ? gcnt[i] : 0;
  s[t] = v;
  __syncthreads();
  for (int off = 1; off < 1024; off <<= 1) {
    int add = (t >= off) ? s[t - off] : 0;
    __syncthreads();
    s[t] += add;
    __syncthreads();
  }
  if (i < M) gbase[i] = s[t] - v;  // block-local exclusive
  if (t == 1023) bsum[blockIdx.x] = s[t];
}

__global__ void scanB_k(const int* __restrict__ bsum, int* __restrict__ boff, int nb) {
  if (threadIdx.x == 0) {
    int acc = 0;
    for (int b = 0; b < nb; b++) { boff[b] = acc; acc += bsum[b]; }
  }
}

__global__ void scanC_k(int* __restrict__ gbase, const int* __restrict__ boff,
                        int* __restrict__ rowptr, int M, int E) {
  int i = blockIdx.x * 256 + threadIdx.x;
  if (i < M) gbase[i] += boff[i >> 10];
  if (i == 0) { gbase[M] = E; rowptr[0] = 0; }
}

// S3: append into block-private reservations (LDS cursors, NO global atomics)
// int4/float4 loads: 4 edges per iteration per thread.
// rec = { (loc 9b << 23) | src (23b), ae fp32 } packed in one int2
__device__ __forceinline__ int packrec(int d, int sv) {
  return (int)(((unsigned)(d & (SBN - 1)) << 23) | (unsigned)sv);
}

__global__ __launch_bounds__(256) void append2_k(
    const int* __restrict__ src, const int* __restrict__ dst,
    const float* __restrict__ eattr, const int* __restrict__ gbase,
    int2* __restrict__ recDS, const float* __restrict__ sw, int E, int NSB, int CE) {
  __shared__ int base[MAXSB];
  __shared__ int off[MAXSB];
  const int t = threadIdx.x, blk = blockIdx.x;
  for (int i = t; i < NSB; i += 256) { base[i] = gbase[i * NB1 + blk]; off[i] = 0; }
  __syncthreads();
  const float w0 = sw[0], w1 = sw[1], w2 = sw[2];
  const int e0 = blk * CE;
  const int e1 = min(E, e0 + CE);
  const int len = e1 - e0;
  if (len > 0) {
    const int NQ = len >> 2;
    for (int i = t; i < NQ; i += 256) {
      const int e = e0 + 4 * i;
      int4 d4 = *(const int4*)&dst[e];
      int4 s4 = *(const int4*)&src[e];
      float4 f0 = *(const float4*)&eattr[(size_t)e * 3];
      float4 f1 = *(const float4*)&eattr[(size_t)e * 3 + 4];
      float4 f2 = *(const float4*)&eattr[(size_t)e * 3 + 8];
      float ae0 = f0.x * w0 + f0.y * w1 + f0.z * w2;
      float ae1 = f0.w * w0 + f1.x * w1 + f1.y * w2;
      float ae2 = f1.z * w0 + f1.w * w1 + f2.x * w2;
      float ae3 = f2.y * w0 + f2.z * w1 + f2.w * w2;
      int sb0 = d4.x >> SBSH, sb1 = d4.y >> SBSH;
      int sb2 = d4.z >> SBSH, sb3 = d4.w >> SBSH;
      int p0 = base[sb0] + atomicAdd(&off[sb0], 1);
      recDS[p0] = make_int2(packrec(d4.x, s4.x), __float_as_int(ae0));
      int p1 = base[sb1] + atomicAdd(&off[sb1], 1);
      recDS[p1] = make_int2(packrec(d4.y, s4.y), __float_as_int(ae1));
      int p2 = base[sb2] + atomicAdd(&off[sb2], 1);
      recDS[p2] = make_int2(packrec(d4.z, s4.z), __float_as_int(ae2));
      int p3 = base[sb3] + atomicAdd(&off[sb3], 1);
      recDS[p3] = make_int2(packrec(d4.w, s4.w), __float_as_int(ae3));
    }
    const int rem = len & 3;
    if (t < rem) {
      const int e = e0 + (NQ << 2) + t;
      int d = dst[e], sv = src[e];
      float ae = eattr[(size_t)e * 3] * w0 + eattr[(size_t)e * 3 + 1] * w1 +
                 eattr[(size_t)e * 3 + 2] * w2;
      int sb = d >> SBSH;
      int pos = base[sb] + atomicAdd(&off[sb], 1);
      recDS[pos] = make_int2(packrec(d, sv), __float_as_int(ae));
    }
  }
}

// S4: one block per super-bucket: count 512 nodes, block-scan -> rowptr,
// place final edge[] = (src, layer-1 ex); asum (raw attr) + esum (Σ ex) in LDS.
__global__ __launch_bounds__(1024) void sb_build_k(
    const int2* __restrict__ recDS, const int* __restrict__ gbase,
    const float* __restrict__ asrc, const float* __restrict__ adst,
    int* __restrict__ rowptr, float* __restrict__ asum, float* __restrict__ esum,
    int2* __restrict__ edge, int n, int NSB) {
  __shared__ int cnt[SBN];
  __shared__ int sc[SBN];
  __shared__ int fill[SBN];
  __shared__ float adl[SBN];
  __shared__ float rs[SBN];
  __shared__ float es[SBN];
  const int t = threadIdx.x, sb = blockIdx.x;
  const int v0 = sb << SBSH;
  const int nloc = min(SBN, n - v0);
  if (t < SBN) {
    cnt[t] = 0; fill[t] = 0; rs[t] = 0.f; es[t] = 0.f;
    adl[t] = (t < nloc) ? adst[v0 + t] : 0.f;
  }
  __syncthreads();
  const int seg0 = gbase[sb * NB1], seg1 = gbase[(sb + 1) * NB1];
  for (int i = seg0 + t; i < seg1; i += 1024)
    atomicAdd(&cnt[(unsigned)recDS[i].x >> 23], 1);
  __syncthreads();
  if (t < SBN) sc[t] = cnt[t];
  __syncthreads();
  for (int off = 1; off < SBN; off <<= 1) {
    int add = (t < SBN && t >= off) ? sc[t - off] : 0;
    __syncthreads();
    if (t < SBN) sc[t] += add;
    __syncthreads();
  }
  if (t < nloc) rowptr[v0 + t + 1] = seg0 + sc[t];
  for (int i = seg0 + t; i < seg1; i += 1024) {
    int2 rec = recDS[i];
    unsigned q = (unsigned)rec.x;
    float ae = __int_as_float(rec.y);
    int loc = q >> 23;
    int sv = (int)(q & 0x7FFFFFu);
    int pos = seg0 + (sc[loc] - cnt[loc]) + atomicAdd(&fill[loc], 1);
    float ex = __expf(LRELU(asrc[sv] + adl[loc] + ae));
    edge[pos] = make_int2(sv, __float_as_int(ex));
    atomicAdd(&rs[loc], ae);
    atomicAdd(&es[loc], ex);
  }
  __syncthreads();
  if (t < nloc) { asum[v0 + t] = rs[t]; esum[v0 + t] = es[t]; }
}

// ---------------- layer-1 GEMM: x [n,5] @ W [5,64] (wave per node) -------------

__global__ void gemm1_k(const float* __restrict__ x, const float* __restrict__ W,
                        const float* __restrict__ as, const float* __restrict__ ad,
                        __half* __restrict__ h, float* __restrict__ asrc,
                        float* __restrict__ adst, int n) {
  int lane = threadIdx.x & 63;
  int v = (blockIdx.x * blockDim.x + threadIdx.x) >> 6;
  if (v >= n) return;
  float acc = 0.f;
#pragma unroll
  for (int k = 0; k < 5; k++) acc += x[v * 5 + k] * W[k * 64 + lane];
  h[(size_t)v * 64 + lane] = __float2half(acc);
  float ps = acc * as[lane], pd = acc * ad[lane];
#pragma unroll
  for (int off = 32; off > 0; off >>= 1) {
    ps += __shfl_down(ps, off);
    pd += __shfl_down(pd, off);
  }
  if (lane == 0) { asrc[v] = ps; adst[v] = pd; }
}

// ------- tiled GEMM: x [n,64] (fp16) @ W [64,C] (fp32), 4x4 register blocking --

template <int C>
__global__ __launch_bounds__(256) void gemm_tile_k(
    const __half* __restrict__ x, const float* __restrict__ W,
    const float* __restrict__ as, const float* __restrict__ ad,
    __half* __restrict__ h, float* __restrict__ asrc, float* __restrict__ adst, int n) {
  constexpr int NT = 4096 / C;
  constexpr int CG = C / 4;
  constexpr int XTP = NT + 4;
  __shared__ float XT[64][XTP];
  __shared__ float Wl[64 * C];
  const int t = threadIdx.x;
  const int v0 = blockIdx.x * NT;
  for (int i = t; i < 64 * C; i += 256) Wl[i] = W[i];
  for (int i = t; i < NT * 32; i += 256) {
    int node = i >> 5, kk = (i & 31) << 1;
    int v = v0 + node;
    unsigned u = (v < n) ? *(const unsigned*)&x[(size_t)v * 64 + kk] : 0u;
    float2 f = __half22float2(*(const __half2*)&u);
    XT[kk][node] = f.x;
    XT[kk + 1][node] = f.y;
  }
  __syncthreads();
  const int cg = t % CG, ng = t / CG;
  const int c0 = cg * 4, n0 = ng * 4;
  float acc[4][4] = {};
#pragma unroll 4
  for (int k = 0; k < 64; ++k) {
    const float4 xv = *(const float4*)&XT[k][n0];
    const float4 wv = *(const float4*)&Wl[k * C + c0];
    acc[0][0] += xv.x * wv.x; acc[0][1] += xv.x * wv.y; acc[0][2] += xv.x * wv.z; acc[0][3] += xv.x * wv.w;
    acc[1][0] += xv.y * wv.x; acc[1][1] += xv.y * wv.y; acc[1][2] += xv.y * wv.z; acc[1][3] += xv.y * wv.w;
    acc[2][0] += xv.z * wv.x; acc[2][1] += xv.z * wv.y; acc[2][2] += xv.z * wv.z; acc[2][3] += xv.z * wv.w;
    acc[3][0] += xv.w * wv.x; acc[3][1] += xv.w * wv.y; acc[3][2] += xv.w * wv.z; acc[3][3] += xv.w * wv.w;
  }
  float asv[4] = {as[c0], as[c0 + 1], as[c0 + 2], as[c0 + 3]};
  float adv[4] = {ad[c0], ad[c0 + 1], ad[c0 + 2], ad[c0 + 3]};
  float ps[4], pd[4];
#pragma unroll
  for (int ni = 0; ni < 4; ++ni) {
    ps[ni] = acc[ni][0] * asv[0] + acc[ni][1] * asv[1] + acc[ni][2] * asv[2] + acc[ni][3] * asv[3];
    pd[ni] = acc[ni][0] * adv[0] + acc[ni][1] * adv[1] + acc[ni][2] * adv[2] + acc[ni][3] * adv[3];
  }
#pragma unroll
  for (int off = CG / 2; off > 0; off >>= 1) {
#pragma unroll
    for (int ni = 0; ni < 4; ++ni) {
      ps[ni] += __shfl_xor(ps[ni], off);
      pd[ni] += __shfl_xor(pd[ni], off);
    }
  }
#pragma unroll
  for (int ni = 0; ni < 4; ++ni) {
    int v = v0 + n0 + ni;
    if (v < n) {
      union { __half hh[4]; uint2 u; } pk;
      pk.hh[0] = __float2half(acc[ni][0]);
      pk.hh[1] = __float2half(acc[ni][1]);
      pk.hh[2] = __float2half(acc[ni][2]);
      pk.hh[3] = __float2half(acc[ni][3]);
      *(uint2*)&h[(size_t)v * C + c0] = pk.u;
      if (cg == 0) { asrc[v] = ps[ni]; adst[v] = pd[ni]; }
    }
  }
}

// 8 fp16 channels FMA into 4 float2 accumulators
__device__ __forceinline__ void fma8(float2* acc, float e, const uint4& u) {
  float2 f0 = __half22float2(*(const __half2*)&u.x);
  float2 f1 = __half22float2(*(const __half2*)&u.y);
  float2 f2 = __half22float2(*(const __half2*)&u.z);
  float2 f3 = __half22float2(*(const __half2*)&u.w);
  acc[0].x += e * f0.x; acc[0].y += e * f0.y;
  acc[1].x += e * f1.x; acc[1].y += e * f1.y;
  acc[2].x += e * f2.x; acc[2].y += e * f2.y;
  acc[3].x += e * f3.x; acc[3].y += e * f3.y;
}

// ---------------- per-node softmax + aggregate (round-10 structure) -----------
// edge[p] = (src, ex). LAYER=1: ex & den (esum) precomputed by sb_build — NO
// pass A. LAYER>=2: pass A lane-parallel (1 edge/lane/iter), in-place ex update.
// Deferred normalization via pinv/oinv. Pass B: row-gather groups, 2 chains.
// out: fp16 for LAYER<3 (next GEMM input), fp32 for LAYER==3 (pool input).
template <int LAYER, int C>
__global__ __launch_bounds__(256) void agg_k(
    const int* __restrict__ rowptr, int2* __restrict__ edge,
    const __half* __restrict__ h, const float* __restrict__ asrc,
    const float* __restrict__ adst, const float* __restrict__ asum,
    const float* __restrict__ esum, const float* __restrict__ pinv,
    const float* __restrict__ lp1, const float* __restrict__ lp2,
    float* __restrict__ oinv, float* __restrict__ ol1, float* __restrict__ ol2,
    const float* __restrict__ sw, const float* __restrict__ bias,
    void* __restrict__ outv, int n) {
  constexpr int L = (C == 64) ? 64 : 32;   // lanes per node
  constexpr int LPE = C / 8;               // lanes per h row (8 / 4)
  constexpr int EPI = L / LPE;             // edges per iteration (8)
  const int lane = threadIdx.x & 63;
  const int ln = lane & (L - 1);
  const int wid = (blockIdx.x * blockDim.x + threadIdx.x) >> 6;
  const int v = (C == 64) ? wid : wid * 2 + (lane >> 5);
  if (v >= n) return;
  const float s = (LAYER == 1) ? 1.f : (LAYER == 2 ? sw[3] : sw[4]);
  const float fac = (LAYER == 1) ? 1.f : pinv[v];
  const float sf = s * fac;
  const int r0 = rowptr[v], r1 = rowptr[v + 1];
  const float av_d = adst[v], av_s = asrc[v];

  // pass A (lane-parallel over edges); layer 1 skips it (den from esum)
  float rawsum = 0.f, den = 0.f;
  if (LAYER >= 2) {
    for (int p = r0 + ln; p < r1; p += L) {
      int2 pk = edge[p];
      float a = __int_as_float(pk.y);
      rawsum += a;
      float lg = asrc[pk.x] + av_d + sf * a;
      float ex = __expf(LRELU(lg));
      edge[p].y = __float_as_int(ex);
      den += ex;
    }
    __threadfence_block();
#pragma unroll
    for (int off = L / 2; off > 0; off >>= 1) {
      den += __shfl_xor(den, off);
      rawsum += __shfl_xor(rawsum, off);
    }
  } else {
    den = esum[v];
  }
  const float base = av_s + av_d;
  float la1 = 0.f, la2 = 0.f, e1 = 0.f, e2 = 0.f;
  if (LAYER >= 2) { la1 = fac * lp1[v]; e1 = __expf(LRELU(base + s * la1)); den += e1; }
  if (LAYER >= 3) { la2 = fac * lp2[v]; e2 = __expf(LRELU(base + s * la2)); den += e2; }
  int dd = (r1 - r0) + (LAYER - 1);
  if (dd < 1) dd = 1;
  float sum_a = (LAYER == 1) ? asum[v] : fac * rawsum + la1 + la2;
  float lmean = sum_a / (float)dd;
  float exm = __expf(LRELU(base + s * lmean));
  den += exm;
  float inv = 1.f / (den + 1e-16f);
  if (ln == 0) {
    if (LAYER < 3) oinv[v] = inv;
    if (LAYER == 1) ol1[v] = exm;
    if (LAYER == 2) { ol1[v] = e1; ol2[v] = exm; }
  }

  // pass B: group g handles edge p+g; lane's quad q covers channels [8q, 8q+8)
  const int g = ln / LPE;
  const int q = ln % LPE;
  const uint4* __restrict__ h4 = (const uint4*)h;
  float2 accA[4] = {{0.f,0.f},{0.f,0.f},{0.f,0.f},{0.f,0.f}};
  float2 accB[4] = {{0.f,0.f},{0.f,0.f},{0.f,0.f},{0.f,0.f}};
  int p = r0;
  for (; p + 2 * EPI <= r1; p += 2 * EPI) {
    int2 rA = edge[p + g];
    int2 rB = edge[p + EPI + g];
    uint4 uA = h4[rA.x * LPE + q];
    uint4 uB = h4[rB.x * LPE + q];
    fma8(accA, __int_as_float(rA.y), uA);
    fma8(accB, __int_as_float(rB.y), uB);
  }
  for (; p < r1; p += EPI) {
    int idx = p + g;
    float e_;
    int2 rr;
    if (idx < r1) { rr = edge[idx]; e_ = __int_as_float(rr.y); }
    else { rr = edge[r1 - 1]; e_ = 0.f; }
    uint4 u = h4[rr.x * LPE + q];
    fma8(accA, e_, u);
  }
#pragma unroll
  for (int j = 0; j < 4; ++j) {
    accA[j].x += accB[j].x;
    accA[j].y += accB[j].y;
  }
#pragma unroll
  for (int off = LPE; off < L; off <<= 1) {
#pragma unroll
    for (int j = 0; j < 4; ++j) {
      accA[j].x += __shfl_xor(accA[j].x, off);
      accA[j].y += __shfl_xor(accA[j].y, off);
    }
  }
  if (g == 0) {
    uint4 uh = h4[v * LPE + q];
    float2 f0 = __half22float2(*(const __half2*)&uh.x);
    float2 f1 = __half22float2(*(const __half2*)&uh.y);
    float2 f2 = __half22float2(*(const __half2*)&uh.z);
    float2 f3 = __half22float2(*(const __half2*)&uh.w);
    float sl = e1 + e2 + exm;
    float o[8];
    o[0] = (accA[0].x + sl * f0.x) * inv + bias[q * 8 + 0];
    o[1] = (accA[0].y + sl * f0.y) * inv + bias[q * 8 + 1];
    o[2] = (accA[1].x + sl * f1.x) * inv + bias[q * 8 + 2];
    o[3] = (accA[1].y + sl * f1.y) * inv + bias[q * 8 + 3];
    o[4] = (accA[2].x + sl * f2.x) * inv + bias[q * 8 + 4];
    o[5] = (accA[2].y + sl * f2.y) * inv + bias[q * 8 + 5];
    o[6] = (accA[3].x + sl * f3.x) * inv + bias[q * 8 + 6];
    o[7] = (accA[3].y + sl * f3.y) * inv + bias[q * 8 + 7];
    if (LAYER < 3) {  // relu + fp16 store (next layer's GEMM input)
      union { __half hh[8]; uint4 u; } pk;
#pragma unroll
      for (int j = 0; j < 8; ++j) pk.hh[j] = __float2half(fmaxf(o[j], 0.f));
      *(uint4*)&((__half*)outv)[(size_t)v * C + q * 8] = pk.u;
    } else {          // final layer: fp32 for pooling
      float4 o0 = make_float4(o[0], o[1], o[2], o[3]);
      float4 o1 = make_float4(o[4], o[5], o[6], o[7]);
      *(float4*)&((float*)outv)[(size_t)v * C + q * 8] = o0;
      *(float4*)&((float*)outv)[(size_t)v * C + q * 8 + 4] = o1;
    }
  }
}

// ---------------- global mean pool, two-stage (deterministic) ----------------

__global__ __launch_bounds__(256) void poolA_k(const float* __restrict__ h,
                                               const int* __restrict__ batch,
                                               float* __restrict__ partial, int n) {
  const int b = blockIdx.x;
  const int g = b / PC, ch = b % PC;
  int lo = 0, hi = n;
  while (lo < hi) { int m = (lo + hi) >> 1; if (batch[m] < g) lo = m + 1; else hi = m; }
  const int start = lo;
  hi = n;
  while (lo < hi) { int m = (lo + hi) >> 1; if (batch[m] < g + 1) lo = m + 1; else hi = m; }
  const int end = lo;
  const int len = end - start;
  const int c0 = start + (int)((long long)len * ch / PC);
  const int c1 = start + (int)((long long)len * (ch + 1) / PC);
  const int t = threadIdx.x;
  const int c = t & 31, r = t >> 5;
  float acc = 0.f;
  for (int v = c0 + r; v < c1; v += 8) acc += h[(size_t)v * 32 + c];
  __shared__ float sm[256];
  sm[t] = acc;
  __syncthreads();
  if (t < 128) sm[t] += sm[t + 128];
  __syncthreads();
  if (t < 64) sm[t] += sm[t + 64];
  __syncthreads();
  if (t < 32) partial[(b << 5) + t] = sm[t] + sm[t + 32];
}

__global__ void poolB_k(const float* __restrict__ partial, const int* __restrict__ batch,
                        float* __restrict__ out, int n) {
  const int g = blockIdx.x;
  const int t = threadIdx.x;
  if (t >= 32) return;
  int lo = 0, hi = n;
  while (lo < hi) { int m = (lo + hi) >> 1; if (batch[m] < g) lo = m + 1; else hi = m; }
  const int start = lo;
  hi = n;
  while (lo < hi) { int m = (lo + hi) >> 1; if (batch[m] < g + 1) lo = m + 1; else hi = m; }
  const int cnt = lo - start;
  float acc = 0.f;
#pragma unroll
  for (int ch = 0; ch < PC; ++ch) acc += partial[((g * PC + ch) << 5) + t];
  out[g * 32 + t] = acc / (float)(cnt > 0 ? cnt : 1);
}

// ---------------- launch ----------------

extern "C" void kernel_launch(void* const* d_in, const int* in_sizes, int n_in,
                              void* d_out, int out_size, void* d_ws, size_t ws_size,
                              hipStream_t stream) {
  const float* x     = (const float*)d_in[0];
  const int*   ei    = (const int*)d_in[1];
  const float* eattr = (const float*)d_in[2];
  const int*   batch = (const int*)d_in[3];
  const float *W1 = (const float*)d_in[4],  *as1 = (const float*)d_in[5],
              *ad1 = (const float*)d_in[6], *We1 = (const float*)d_in[7],
              *ae1 = (const float*)d_in[8], *b1  = (const float*)d_in[9];
  const float *W2 = (const float*)d_in[10], *as2 = (const float*)d_in[11],
              *ad2 = (const float*)d_in[12], *We2 = (const float*)d_in[13],
              *ae2 = (const float*)d_in[14], *b2  = (const float*)d_in[15];
  const float *W3 = (const float*)d_in[16], *as3 = (const float*)d_in[17],
              *ad3 = (const float*)d_in[18], *We3 = (const float*)d_in[19],
              *ae3 = (const float*)d_in[20], *b3  = (const float*)d_in[21];

  const int n = in_sizes[3];
  const int E = in_sizes[1] / 2;
  const int G = out_size / 32;
  const int* srcp = ei;
  const int* dstp = ei + E;
  const int NSB = (n + SBN - 1) >> SBSH;
  const int M = NSB * NB1;
  const int NBL = (M + 1023) / 1024;
  const int CE4 = (((E + NB1 - 1) / NB1) + 3) & ~3;  // 16B-aligned chunk per block

  char* w = (char*)d_ws;
  auto alloc = [&](size_t bytes) -> void* {
    void* p = (void*)w;
    w += (bytes + 255) & ~(size_t)255;
    return p;
  };
  // blob: staging recDS; after sb_build reused as Oh (fp16 inter) + O32 (final)
  size_t oh_bytes = ((size_t)n * 128 + 255) & ~(size_t)255;
  size_t blob_sz = (size_t)E * 8;
  if (blob_sz < oh_bytes + (size_t)n * 128) blob_sz = oh_bytes + (size_t)n * 128;
  char* blob = (char*)alloc(blob_sz);
  int2*   recDS = (int2*)blob;
  __half* Oh    = (__half*)blob;                    // n x 64 fp16
  float*  O32   = (float*)(blob + oh_bytes);        // n x 32 fp32
  int2*  edge  = (int2*)alloc((size_t)E * 8);
  __half* H    = (__half*)alloc((size_t)n * 64 * 2);
  int*   gcnt  = (int*)alloc((size_t)M * 4);
  int*   gbase = (int*)alloc((size_t)(M + 1) * 4);
  int*   bsum  = (int*)alloc((size_t)NBL * 4 + 256);
  int*   boff  = (int*)alloc((size_t)NBL * 4 + 256);
  int*   rowptr= (int*)alloc((size_t)(n + 1) * 4);
  float* asum  = (float*)alloc((size_t)n * 4);
  float* esum  = (float*)alloc((size_t)n * 4);
  float* asrcB = (float*)alloc((size_t)n * 4);
  float* adstB = (float*)alloc((size_t)n * 4);
  float* loopA = (float*)alloc((size_t)n * 4);
  float* loopB1= (float*)alloc((size_t)n * 4);
  float* loopB2= (float*)alloc((size_t)n * 4);
  float* invA  = (float*)alloc((size_t)n * 4);
  float* invB  = (float*)alloc((size_t)n * 4);
  float* sw    = (float*)alloc(256);
  float* part  = (float*)alloc((size_t)G * PC * 32 * 4);

  dim3 blk256(256);
  dim3 gWave((n + 3) / 4);
  const int nw3 = (n + 1) / 2;
  dim3 gWave3((nw3 + 3) / 4);

  small_weights_k<<<1, 64, 0, stream>>>(We1, ae1, We2, ae2, We3, ae3, sw);
  count1_k<<<NB1, blk256, 0, stream>>>(dstp, gcnt, E, NSB, CE4);
  scanA_k<<<NBL, 1024, 0, stream>>>(gcnt, gbase, bsum, M);
  scanB_k<<<1, 64, 0, stream>>>(bsum, boff, NBL);
  scanC_k<<<dim3((M + 256) / 256), blk256, 0, stream>>>(gbase, boff, rowptr, M, E);
  append2_k<<<NB1, blk256, 0, stream>>>(srcp, dstp, eattr, gbase, recDS, sw, E, NSB, CE4);
  gemm1_k<<<gWave, blk256, 0, stream>>>(x, W1, as1, ad1, H, asrcB, adstB, n);
  sb_build_k<<<NSB, 1024, 0, stream>>>(recDS, gbase, asrcB, adstB,
                                       rowptr, asum, esum, edge, n, NSB);
  // layer 1 (out -> Oh fp16)
  agg_k<1, 64><<<gWave, blk256, 0, stream>>>(rowptr, edge, H, asrcB, adstB, asum, esum,
                                             nullptr, nullptr, nullptr,
                                             invA, loopA, nullptr, sw, b1, (void*)Oh, n);
  // layer 2
  gemm_tile_k<64><<<dim3((n + 63) / 64), blk256, 0, stream>>>(Oh, W2, as2, ad2, H, asrcB, adstB, n);
  agg_k<2, 64><<<gWave, blk256, 0, stream>>>(rowptr, edge, H, asrcB, adstB, nullptr, nullptr,
                                             invA, loopA, nullptr,
                                             invB, loopB1, loopB2, sw, b2, (void*)Oh, n);
  // layer 3 (out -> O32 fp32)
  gemm_tile_k<32><<<dim3((n + 127) / 128), blk256, 0, stream>>>(Oh, W3, as3, ad3, H, asrcB, adstB, n);
  agg_k<3, 32><<<gWave3, blk256, 0, stream>>>(rowptr, edge, H, asrcB, adstB, nullptr, nullptr,
                                              invB, loopB1, loopB2,
                                              nullptr, nullptr, nullptr, sw, b3, (void*)O32, n);
  // pool
  poolA_k<<<dim3(G * PC), blk256, 0, stream>>>(O32, batch, part, n);
  poolB_k<<<G, 64, 0, stream>>>(part, batch, (float*)d_out, n);
}